// Round 7
// baseline (185.271 us; speedup 1.0000x reference)
//
#include <hip/hip_runtime.h>
#include <hip/hip_cooperative_groups.h>

namespace cg = cooperative_groups;
typedef unsigned long long u64;

// Problem constants (fixed by reference file)
#define N_TRUCK 100000
#define BLK 256
#define NB 256           // buckets per graph
#define NPB 391          // nodes per bucket: ceil(100000/256)
#define CAP 8192         // slots per bucket (mean 6250, sigma ~79 -> 24 sigma slack)
#define PB 512           // chunks == grid blocks == 2*NB
#define BLK_P 1024
#define CHUNK_MAX 3136
#define ROW_MASK 0x1FFFFu
#define LC_SHIFT 17

// ---------------- fused ws layout (bytes) ----------------
// G f32[36] @ 0 | totT i32[256] @ 256 | totC @ 1280
// cntT i32[NB][PB] @ 4096 (524288) | cntC @ 528384 (524288)
// dis_t @ 1052672 | dis_c @ 1452672 | s_t @ 1852672 | y4 @ 2252672 (1600000)
// xs4 @ 3852672 (1600000) | pT @ 5452672 (8388608) | pC8 @ 13841280 (16777216)
#define WS_NEED_F 30618496ULL
// round-6 fallback layout needs:
#define WS_NEED_NEW 29569920ULL

struct FParams {
    const int *trow, *tcol, *crow, *ccol;
    const float* ew;
    const int *src, *dst;
    const float *Wt, *bt, *Wc, *bc, *wlin, *blin;
    const float* x_car;
    float* out;
    int E, P, NC;
    float* G;
    int *totT, *totC, *cntT, *cntC;
    float *dis_t, *dis_c, *s_t;
    float4 *y4, *xs4;
    unsigned* pT;
    u64* pC8;
};

union SmemU {
    struct { int hT[NB]; int hC[NB]; } hist;
    struct { int w[16]; } scan;
    struct {
        u64 pay8[CHUNK_MAX];
        unsigned char bkt[CHUNK_MAX];
        int hist[NB];
        int shift[NB];
        int wsum[16];
    } place;
    struct { float acc[NPB]; } deg;
    struct { float y[NPB * 5]; float dcl[NPB]; } agg;
};

__device__ __forceinline__ void load_zf(int i, const float* __restrict__ s_t,
                                        const float4* __restrict__ y4, float z[6]) {
    if (i < N_TRUCK) {
        z[0] = s_t[i]; z[1] = 1.0f; z[2] = 0.0f; z[3] = 0.0f; z[4] = 0.0f; z[5] = 0.0f;
    } else {
        float4 y = y4[i - N_TRUCK];
        z[0] = 0.0f; z[1] = 0.0f; z[2] = y.x; z[3] = y.y; z[4] = y.z; z[5] = 1.0f;
    }
}

__global__ __launch_bounds__(1024, 8)
void k_fused(FParams fp) {
    cg::grid_group grid = cg::this_grid();
    __shared__ SmemU sm;
    const int t = threadIdx.x;
    const int b = blockIdx.x;
    const int lane = t & 63, wv = t >> 6;
    const int chunk = (fp.E + PB - 1) / PB;
    const int s0 = b * chunk, s1 = min(fp.E, s0 + chunk);
    const int n = s1 - s0;

    // ---------- Phase A: per-chunk histogram of both graphs ----------
    for (int k = t; k < NB; k += BLK_P) { sm.hist.hT[k] = 0; sm.hist.hC[k] = 0; }
    __syncthreads();
    for (int j = s0 + t; j < s1; j += BLK_P) {
        atomicAdd(&sm.hist.hT[fp.tcol[j] / NPB], 1);
        atomicAdd(&sm.hist.hC[fp.ccol[j] / NPB], 1);
    }
    __syncthreads();
    for (int k = t; k < NB; k += BLK_P) {
        fp.cntT[k * PB + b] = sm.hist.hT[k];
        fp.cntC[k * PB + b] = sm.hist.hC[k];
    }
    grid.sync();

    // ---------- Phase C: per-bucket exclusive scan over chunks (+G by blk0/wave8) ----------
    {
        bool car = b >= NB;
        int k = b & (NB - 1);
        int* row = (car ? fp.cntC : fp.cntT) + k * PB;
        int v = 0, inc = 0;
        if (t < PB) {
            v = row[t];
            inc = v;
#pragma unroll
            for (int off = 1; off < 64; off <<= 1) {
                int nv = __shfl_up(inc, off);
                if (lane >= off) inc += nv;
            }
            if (lane == 63) sm.scan.w[wv] = inc;
        } else if (b == 0 && wv == 8) {
            // G[a][b2] = sum_h M[a,h]*M[b2,h]*wlin[h]
            float acc[21];
#pragma unroll
            for (int q = 0; q < 21; q++) acc[q] = 0.0f;
            for (int h = lane; h < 128; h += 64) {
                float m[6] = {fp.Wt[h], fp.bt[h], fp.Wc[h], fp.Wc[128 + h], fp.Wc[256 + h], fp.bc[h]};
                float w = fp.wlin[h];
                int q = 0;
#pragma unroll
                for (int a = 0; a < 6; a++)
#pragma unroll
                    for (int b2 = a; b2 < 6; b2++)
                        acc[q++] += m[a] * m[b2] * w;
            }
            int q = 0;
#pragma unroll
            for (int a = 0; a < 6; a++)
#pragma unroll
                for (int b2 = a; b2 < 6; b2++) {
                    float vv = acc[q++];
#pragma unroll
                    for (int off = 32; off; off >>= 1) vv += __shfl_down(vv, off);
                    if (lane == 0) {
                        fp.G[a * 6 + b2] = vv;
                        fp.G[b2 * 6 + a] = vv;
                    }
                }
        }
        __syncthreads();
        if (t < 8) {
            int pv = sm.scan.w[t], pinc = pv;
#pragma unroll
            for (int off = 1; off < 8; off <<= 1) {
                int nv = __shfl_up(pinc, off);
                if (lane >= off) pinc += nv;
            }
            sm.scan.w[t] = pinc - pv;
        }
        __syncthreads();
        if (t < PB) {
            int excl = (inc - v) + sm.scan.w[wv];
            row[t] = excl;
            if (t == PB - 1) (car ? fp.totC : fp.totT)[k] = excl + v;
        }
    }
    grid.sync();

    // ---------- Phase E: place (LDS counting sort, coalesced flush) ----------
    // truck
    {
        int cntk = 0, gbase = 0, inc = 0;
        if (t < NB) {
            int e0 = fp.cntT[t * PB + b];
            int e1 = (b == PB - 1) ? fp.totT[t] : fp.cntT[t * PB + b + 1];
            cntk = e1 - e0;
            gbase = t * CAP + e0;
            inc = cntk;
#pragma unroll
            for (int off = 1; off < 64; off <<= 1) {
                int nv = __shfl_up(inc, off);
                if (lane >= off) inc += nv;
            }
            if (lane == 63) sm.place.wsum[wv] = inc;
        }
        __syncthreads();
        if (t < 4) {
            int pv = sm.place.wsum[t], pinc = pv;
#pragma unroll
            for (int off = 1; off < 4; off <<= 1) {
                int nv = __shfl_up(pinc, off);
                if (lane >= off) pinc += nv;
            }
            sm.place.wsum[t] = pinc - pv;
        }
        __syncthreads();
        if (t < NB) {
            int lexcl = (inc - cntk) + sm.place.wsum[wv];
            sm.place.hist[t] = lexcl;
            sm.place.shift[t] = gbase - lexcl;
        }
        __syncthreads();
        unsigned* pay4 = (unsigned*)sm.place.pay8;
        for (int j = s0 + t; j < s1; j += BLK_P) {
            int c = fp.tcol[j];
            int k = c / NPB;
            int s = atomicAdd(&sm.place.hist[k], 1);
            pay4[s] = ((unsigned)(c - k * NPB) << LC_SHIFT) | (unsigned)fp.trow[j];
            sm.place.bkt[s] = (unsigned char)k;
        }
        __syncthreads();
        for (int s = t; s < n; s += BLK_P)
            fp.pT[s + sm.place.shift[sm.place.bkt[s]]] = pay4[s];
        __syncthreads();
    }
    // car
    {
        int cntk = 0, gbase = 0, inc = 0;
        if (t < NB) {
            int e0 = fp.cntC[t * PB + b];
            int e1 = (b == PB - 1) ? fp.totC[t] : fp.cntC[t * PB + b + 1];
            cntk = e1 - e0;
            gbase = t * CAP + e0;
            inc = cntk;
#pragma unroll
            for (int off = 1; off < 64; off <<= 1) {
                int nv = __shfl_up(inc, off);
                if (lane >= off) inc += nv;
            }
            if (lane == 63) sm.place.wsum[wv] = inc;
        }
        __syncthreads();
        if (t < 4) {
            int pv = sm.place.wsum[t], pinc = pv;
#pragma unroll
            for (int off = 1; off < 4; off <<= 1) {
                int nv = __shfl_up(pinc, off);
                if (lane >= off) pinc += nv;
            }
            sm.place.wsum[t] = pinc - pv;
        }
        __syncthreads();
        if (t < NB) {
            int lexcl = (inc - cntk) + sm.place.wsum[wv];
            sm.place.hist[t] = lexcl;
            sm.place.shift[t] = gbase - lexcl;
        }
        __syncthreads();
        for (int j = s0 + t; j < s1; j += BLK_P) {
            int c = fp.ccol[j];
            int k = c / NPB;
            int s = atomicAdd(&sm.place.hist[k], 1);
            unsigned lo = ((unsigned)(c - k * NPB) << LC_SHIFT) | (unsigned)fp.crow[j];
            sm.place.pay8[s] = ((u64)__float_as_uint(fp.ew[j]) << 32) | lo;
            sm.place.bkt[s] = (unsigned char)k;
        }
        __syncthreads();
        for (int s = t; s < n; s += BLK_P)
            fp.pC8[s + sm.place.shift[sm.place.bkt[s]]] = sm.place.pay8[s];
    }
    grid.sync();

    // ---------- Phase G: per-bucket degree -> dis (+xs4 for car) ----------
    {
        bool car = b >= NB;
        int bk = car ? b - NB : b;
        int cnt = car ? fp.totC[bk] : fp.totT[bk];
        int base = bk * CAP;
        for (int k = t; k < NPB; k += BLK_P) sm.deg.acc[k] = 0.0f;
        __syncthreads();
        if (car) {
            const ulonglong4* p4 = (const ulonglong4*)(fp.pC8 + base);
            int q = cnt >> 2;
            for (int j = t; j < q; j += BLK_P) {
                ulonglong4 v = p4[j];
                atomicAdd(&sm.deg.acc[((unsigned)v.x) >> LC_SHIFT], __uint_as_float((unsigned)(v.x >> 32)));
                atomicAdd(&sm.deg.acc[((unsigned)v.y) >> LC_SHIFT], __uint_as_float((unsigned)(v.y >> 32)));
                atomicAdd(&sm.deg.acc[((unsigned)v.z) >> LC_SHIFT], __uint_as_float((unsigned)(v.z >> 32)));
                atomicAdd(&sm.deg.acc[((unsigned)v.w) >> LC_SHIFT], __uint_as_float((unsigned)(v.w >> 32)));
            }
            for (int j = (q << 2) + t; j < cnt; j += BLK_P) {
                u64 v = fp.pC8[base + j];
                atomicAdd(&sm.deg.acc[((unsigned)v) >> LC_SHIFT], __uint_as_float((unsigned)(v >> 32)));
            }
        } else {
            const uint4* p4 = (const uint4*)(fp.pT + base);
            int q = cnt >> 2;
            for (int j = t; j < q; j += BLK_P) {
                uint4 v = p4[j];
                atomicAdd(&sm.deg.acc[v.x >> LC_SHIFT], 1.0f);
                atomicAdd(&sm.deg.acc[v.y >> LC_SHIFT], 1.0f);
                atomicAdd(&sm.deg.acc[v.z >> LC_SHIFT], 1.0f);
                atomicAdd(&sm.deg.acc[v.w >> LC_SHIFT], 1.0f);
            }
            for (int j = (q << 2) + t; j < cnt; j += BLK_P)
                atomicAdd(&sm.deg.acc[fp.pT[base + j] >> LC_SHIFT], 1.0f);
        }
        __syncthreads();
        int ntot = car ? fp.NC : N_TRUCK;
        for (int nn = t; nn < NPB; nn += BLK_P) {
            int node = bk * NPB + nn;
            if (node < ntot) {
                float d = rsqrtf(sm.deg.acc[nn] + 1.0f);
                if (car) {
                    fp.dis_c[node] = d;
                    const float* xn = &fp.x_car[3 * node];
                    fp.xs4[node] = make_float4(d * xn[0], d * xn[1], d * xn[2], d);
                } else {
                    fp.dis_t[node] = d;
                }
            }
        }
    }
    grid.sync();

    // ---------- Phase I: per-bucket aggregation -> s_t / y4 ----------
    if (b < NB) {
        int cnt = fp.totT[b];
        int base = b * CAP;
        for (int k = t; k < NPB; k += BLK_P) sm.deg.acc[k] = 0.0f;
        __syncthreads();
        const uint4* p4 = (const uint4*)(fp.pT + base);
        int q = cnt >> 2;
        for (int j = t; j < q; j += BLK_P) {
            uint4 v = p4[j];
            float d0 = fp.dis_t[v.x & ROW_MASK];
            float d1 = fp.dis_t[v.y & ROW_MASK];
            float d2 = fp.dis_t[v.z & ROW_MASK];
            float d3 = fp.dis_t[v.w & ROW_MASK];
            atomicAdd(&sm.deg.acc[v.x >> LC_SHIFT], d0);
            atomicAdd(&sm.deg.acc[v.y >> LC_SHIFT], d1);
            atomicAdd(&sm.deg.acc[v.z >> LC_SHIFT], d2);
            atomicAdd(&sm.deg.acc[v.w >> LC_SHIFT], d3);
        }
        for (int j = (q << 2) + t; j < cnt; j += BLK_P) {
            unsigned v = fp.pT[base + j];
            atomicAdd(&sm.deg.acc[v >> LC_SHIFT], fp.dis_t[v & ROW_MASK]);
        }
        __syncthreads();
        for (int nn = t; nn < NPB; nn += BLK_P) {
            int node = b * NPB + nn;
            if (node < N_TRUCK) {
                float d = fp.dis_t[node];
                fp.s_t[node] = fmaf(d, sm.deg.acc[nn], d * d);
            }
        }
    } else {
        int bk = b - NB;
        int cnt = fp.totC[bk];
        int base = bk * CAP;
        for (int k = t; k < NPB * 5; k += BLK_P) sm.agg.y[k] = 0.0f;
        for (int k = t; k < NPB; k += BLK_P) {
            int node = bk * NPB + k;
            sm.agg.dcl[k] = (node < fp.NC) ? fp.dis_c[node] : 0.0f;
        }
        __syncthreads();
        const ulonglong4* p4 = (const ulonglong4*)(fp.pC8 + base);
        int q = cnt >> 2;
        for (int j = t; j < q; j += BLK_P) {
            ulonglong4 v = p4[j];
            unsigned lo0 = (unsigned)v.x, lo1 = (unsigned)v.y;
            unsigned lo2 = (unsigned)v.z, lo3 = (unsigned)v.w;
            float4 x0 = fp.xs4[lo0 & ROW_MASK];
            float4 x1 = fp.xs4[lo1 & ROW_MASK];
            float4 x2 = fp.xs4[lo2 & ROW_MASK];
            float4 x3 = fp.xs4[lo3 & ROW_MASK];
            int c0 = lo0 >> LC_SHIFT, c1 = lo1 >> LC_SHIFT;
            int c2 = lo2 >> LC_SHIFT, c3 = lo3 >> LC_SHIFT;
            float n0 = __uint_as_float((unsigned)(v.x >> 32)) * sm.agg.dcl[c0];
            float n1 = __uint_as_float((unsigned)(v.y >> 32)) * sm.agg.dcl[c1];
            float n2 = __uint_as_float((unsigned)(v.z >> 32)) * sm.agg.dcl[c2];
            float n3 = __uint_as_float((unsigned)(v.w >> 32)) * sm.agg.dcl[c3];
            atomicAdd(&sm.agg.y[c0 * 5 + 0], n0 * x0.x);
            atomicAdd(&sm.agg.y[c0 * 5 + 1], n0 * x0.y);
            atomicAdd(&sm.agg.y[c0 * 5 + 2], n0 * x0.z);
            atomicAdd(&sm.agg.y[c1 * 5 + 0], n1 * x1.x);
            atomicAdd(&sm.agg.y[c1 * 5 + 1], n1 * x1.y);
            atomicAdd(&sm.agg.y[c1 * 5 + 2], n1 * x1.z);
            atomicAdd(&sm.agg.y[c2 * 5 + 0], n2 * x2.x);
            atomicAdd(&sm.agg.y[c2 * 5 + 1], n2 * x2.y);
            atomicAdd(&sm.agg.y[c2 * 5 + 2], n2 * x2.z);
            atomicAdd(&sm.agg.y[c3 * 5 + 0], n3 * x3.x);
            atomicAdd(&sm.agg.y[c3 * 5 + 1], n3 * x3.y);
            atomicAdd(&sm.agg.y[c3 * 5 + 2], n3 * x3.z);
        }
        for (int j = (q << 2) + t; j < cnt; j += BLK_P) {
            u64 v = fp.pC8[base + j];
            unsigned lo = (unsigned)v;
            float4 xa = fp.xs4[lo & ROW_MASK];
            int lc = lo >> LC_SHIFT;
            float na = __uint_as_float((unsigned)(v >> 32)) * sm.agg.dcl[lc];
            atomicAdd(&sm.agg.y[lc * 5 + 0], na * xa.x);
            atomicAdd(&sm.agg.y[lc * 5 + 1], na * xa.y);
            atomicAdd(&sm.agg.y[lc * 5 + 2], na * xa.z);
        }
        __syncthreads();
        for (int nn = t; nn < NPB; nn += BLK_P) {
            int node = bk * NPB + nn;
            if (node < fp.NC) {
                float d = sm.agg.dcl[nn];
                float4 xs = fp.xs4[node];
                fp.y4[node] = make_float4(fmaf(d, xs.x, sm.agg.y[nn * 5 + 0]),
                                          fmaf(d, xs.y, sm.agg.y[nn * 5 + 1]),
                                          fmaf(d, xs.z, sm.agg.y[nn * 5 + 2]), 1.0f);
            }
        }
    }
    grid.sync();

    // ---------- Phase K: pair scoring ----------
    float Gl[36];
#pragma unroll
    for (int k = 0; k < 36; k++) Gl[k] = fp.G[k];
    float bl = fp.blin[0];
    for (int p = b * BLK_P + t; p < fp.P; p += gridDim.x * BLK_P) {
        float zs[6], zd[6];
        load_zf(fp.src[p], fp.s_t, fp.y4, zs);
        load_zf(fp.dst[p], fp.s_t, fp.y4, zd);
        float acc = 0.0f;
#pragma unroll
        for (int a = 0; a < 6; a++) {
            float g = 0.0f;
#pragma unroll
            for (int b2 = 0; b2 < 6; b2++) g = fmaf(Gl[a * 6 + b2], zd[b2], g);
            acc = fmaf(zs[a], g, acc);
        }
        fp.out[p] = acc + bl;
    }
}

// ============ round-6 fallback kernels (proven, 184 us) ============

__global__ void k_place(const int* __restrict__ trow, const int* __restrict__ tcol,
                        const int* __restrict__ crow, const int* __restrict__ ccol,
                        const float* __restrict__ ew, int E_,
                        int* __restrict__ curT, int* __restrict__ curC,
                        unsigned* __restrict__ pT, u64* __restrict__ pC8,
                        const float* __restrict__ Wt, const float* __restrict__ bt,
                        const float* __restrict__ Wc, const float* __restrict__ bc,
                        const float* __restrict__ wlin, float* __restrict__ G) {
    if (blockIdx.x == PB) {
        int l = threadIdx.x;
        if (l < 64) {
            float acc[21];
#pragma unroll
            for (int k = 0; k < 21; k++) acc[k] = 0.0f;
            for (int h = l; h < 128; h += 64) {
                float m[6] = {Wt[h], bt[h], Wc[h], Wc[128 + h], Wc[256 + h], bc[h]};
                float w = wlin[h];
                int k = 0;
#pragma unroll
                for (int a = 0; a < 6; a++)
#pragma unroll
                    for (int b2 = a; b2 < 6; b2++)
                        acc[k++] += m[a] * m[b2] * w;
            }
            int k = 0;
#pragma unroll
            for (int a = 0; a < 6; a++)
#pragma unroll
                for (int b2 = a; b2 < 6; b2++) {
                    float v = acc[k++];
#pragma unroll
                    for (int off = 32; off; off >>= 1) v += __shfl_down(v, off);
                    if (l == 0) {
                        G[a * 6 + b2] = v;
                        G[b2 * 6 + a] = v;
                    }
                }
        }
        return;
    }

    __shared__ u64 pay8[CHUNK_MAX];
    __shared__ unsigned char bkt[CHUNK_MAX];
    __shared__ int hist[NB];
    __shared__ int shiftA[NB];
    unsigned* pay4 = (unsigned*)pay8;

    int b = blockIdx.x;
    int chunk = (E_ + PB - 1) / PB;
    int s0 = b * chunk, s1 = min(E_, s0 + chunk);
    int n = s1 - s0;
    int t = threadIdx.x;

    for (int k = t; k < NB; k += BLK_P) hist[k] = 0;
    __syncthreads();
    for (int j = s0 + t; j < s1; j += BLK_P) atomicAdd(&hist[tcol[j] / NPB], 1);
    __syncthreads();
    int myCnt = (t < NB) ? hist[t] : 0;
    if (t < NB) shiftA[t] = myCnt;
    __syncthreads();
    for (int off = 1; off < NB; off <<= 1) {
        int x = (t < NB && t >= off) ? shiftA[t - off] : 0;
        __syncthreads();
        if (t < NB) shiftA[t] += x;
        __syncthreads();
    }
    if (t < NB) {
        int excl = shiftA[t] - myCnt;
        int gstart = t * CAP + atomicAdd(&curT[t], myCnt);
        shiftA[t] = gstart - excl;
        hist[t] = excl;
    }
    __syncthreads();
    for (int j = s0 + t; j < s1; j += BLK_P) {
        int tc = tcol[j];
        int k = tc / NPB;
        int s = atomicAdd(&hist[k], 1);
        pay4[s] = ((unsigned)(tc - k * NPB) << LC_SHIFT) | (unsigned)trow[j];
        bkt[s] = (unsigned char)k;
    }
    __syncthreads();
    for (int s = t; s < n; s += BLK_P)
        pT[s + shiftA[bkt[s]]] = pay4[s];
    __syncthreads();

    for (int k = t; k < NB; k += BLK_P) hist[k] = 0;
    __syncthreads();
    for (int j = s0 + t; j < s1; j += BLK_P) atomicAdd(&hist[ccol[j] / NPB], 1);
    __syncthreads();
    myCnt = (t < NB) ? hist[t] : 0;
    if (t < NB) shiftA[t] = myCnt;
    __syncthreads();
    for (int off = 1; off < NB; off <<= 1) {
        int x = (t < NB && t >= off) ? shiftA[t - off] : 0;
        __syncthreads();
        if (t < NB) shiftA[t] += x;
        __syncthreads();
    }
    if (t < NB) {
        int excl = shiftA[t] - myCnt;
        int gstart = t * CAP + atomicAdd(&curC[t], myCnt);
        shiftA[t] = gstart - excl;
        hist[t] = excl;
    }
    __syncthreads();
    for (int j = s0 + t; j < s1; j += BLK_P) {
        int cc = ccol[j];
        int k = cc / NPB;
        int s = atomicAdd(&hist[k], 1);
        unsigned lo = ((unsigned)(cc - k * NPB) << LC_SHIFT) | (unsigned)crow[j];
        pay8[s] = ((u64)__float_as_uint(ew[j]) << 32) | lo;
        bkt[s] = (unsigned char)k;
    }
    __syncthreads();
    for (int s = t; s < n; s += BLK_P)
        pC8[s + shiftA[bkt[s]]] = pay8[s];
}

__global__ void k_deg2(const unsigned* __restrict__ pT, const u64* __restrict__ pC8,
                       const int* __restrict__ curT, const int* __restrict__ curC,
                       const float* __restrict__ x_car,
                       float* __restrict__ dis_t, float* __restrict__ dis_c,
                       float4* __restrict__ xs4, int nt, int nc) {
    __shared__ float acc[NPB];
    int b = blockIdx.x;
    bool car = b >= NB;
    int bk = car ? b - NB : b;
    int cnt = car ? curC[bk] : curT[bk];
    int s0 = bk * CAP;
    for (int k = threadIdx.x; k < NPB; k += blockDim.x) acc[k] = 0.0f;
    __syncthreads();
    if (car) {
        const ulonglong2* p2 = (const ulonglong2*)(pC8 + s0);
        int half = cnt >> 1;
        for (int j = threadIdx.x; j < half; j += blockDim.x) {
            ulonglong2 v = p2[j];
            atomicAdd(&acc[((unsigned)v.x) >> LC_SHIFT], __uint_as_float((unsigned)(v.x >> 32)));
            atomicAdd(&acc[((unsigned)v.y) >> LC_SHIFT], __uint_as_float((unsigned)(v.y >> 32)));
        }
        if ((cnt & 1) && threadIdx.x == 0) {
            u64 v = pC8[s0 + cnt - 1];
            atomicAdd(&acc[((unsigned)v) >> LC_SHIFT], __uint_as_float((unsigned)(v >> 32)));
        }
    } else {
        const uint2* p2 = (const uint2*)(pT + s0);
        int half = cnt >> 1;
        for (int j = threadIdx.x; j < half; j += blockDim.x) {
            uint2 v = p2[j];
            atomicAdd(&acc[v.x >> LC_SHIFT], 1.0f);
            atomicAdd(&acc[v.y >> LC_SHIFT], 1.0f);
        }
        if ((cnt & 1) && threadIdx.x == 0)
            atomicAdd(&acc[pT[s0 + cnt - 1] >> LC_SHIFT], 1.0f);
    }
    __syncthreads();
    int ntot = car ? nc : nt;
    for (int nn = threadIdx.x; nn < NPB; nn += blockDim.x) {
        int node = bk * NPB + nn;
        if (node < ntot) {
            float d = rsqrtf(acc[nn] + 1.0f);
            if (car) {
                dis_c[node] = d;
                const float* xn = &x_car[3 * node];
                xs4[node] = make_float4(d * xn[0], d * xn[1], d * xn[2], d);
            } else {
                dis_t[node] = d;
            }
        }
    }
}

__global__ void k_agg(const unsigned* __restrict__ pT, const u64* __restrict__ pC8,
                      const int* __restrict__ curT, const int* __restrict__ curC,
                      const float* __restrict__ dis_t, const float* __restrict__ dis_c,
                      const float4* __restrict__ xs4,
                      float* __restrict__ s_t, float4* __restrict__ y4,
                      int nt, int nc) {
    int b = blockIdx.x;
    if (b < NB) {
        __shared__ float sacc[NPB];
        int cnt = curT[b];
        int s0 = b * CAP;
        for (int k = threadIdx.x; k < NPB; k += blockDim.x) sacc[k] = 0.0f;
        __syncthreads();
        const uint2* p2 = (const uint2*)(pT + s0);
        int half = cnt >> 1;
        for (int j = threadIdx.x; j < half; j += blockDim.x) {
            uint2 v = p2[j];
            float da = dis_t[v.x & ROW_MASK];
            float db = dis_t[v.y & ROW_MASK];
            atomicAdd(&sacc[v.x >> LC_SHIFT], da);
            atomicAdd(&sacc[v.y >> LC_SHIFT], db);
        }
        if ((cnt & 1) && threadIdx.x == 0) {
            unsigned v = pT[s0 + cnt - 1];
            atomicAdd(&sacc[v >> LC_SHIFT], dis_t[v & ROW_MASK]);
        }
        __syncthreads();
        for (int nn = threadIdx.x; nn < NPB; nn += blockDim.x) {
            int node = b * NPB + nn;
            if (node < nt) {
                float d = dis_t[node];
                s_t[node] = fmaf(d, sacc[nn], d * d);
            }
        }
    } else {
        int bk = b - NB;
        __shared__ float y[NPB * 5];
        __shared__ float dcl[NPB];
        int cnt = curC[bk];
        int s0 = bk * CAP;
        for (int k = threadIdx.x; k < NPB * 5; k += blockDim.x) y[k] = 0.0f;
        for (int k = threadIdx.x; k < NPB; k += blockDim.x) {
            int node = bk * NPB + k;
            dcl[k] = (node < nc) ? dis_c[node] : 0.0f;
        }
        __syncthreads();
        const ulonglong2* p2 = (const ulonglong2*)(pC8 + s0);
        int half = cnt >> 1;
        for (int j = threadIdx.x; j < half; j += blockDim.x) {
            ulonglong2 v = p2[j];
            unsigned loa = (unsigned)v.x, lob = (unsigned)v.y;
            float4 xa = xs4[loa & ROW_MASK];
            float4 xb = xs4[lob & ROW_MASK];
            int lca = loa >> LC_SHIFT, lcb = lob >> LC_SHIFT;
            float na = __uint_as_float((unsigned)(v.x >> 32)) * dcl[lca];
            float nb = __uint_as_float((unsigned)(v.y >> 32)) * dcl[lcb];
            atomicAdd(&y[lca * 5 + 0], na * xa.x);
            atomicAdd(&y[lca * 5 + 1], na * xa.y);
            atomicAdd(&y[lca * 5 + 2], na * xa.z);
            atomicAdd(&y[lcb * 5 + 0], nb * xb.x);
            atomicAdd(&y[lcb * 5 + 1], nb * xb.y);
            atomicAdd(&y[lcb * 5 + 2], nb * xb.z);
        }
        if ((cnt & 1) && threadIdx.x == 0) {
            u64 v = pC8[s0 + cnt - 1];
            unsigned lo = (unsigned)v;
            float4 xa = xs4[lo & ROW_MASK];
            int lc = lo >> LC_SHIFT;
            float na = __uint_as_float((unsigned)(v >> 32)) * dcl[lc];
            atomicAdd(&y[lc * 5 + 0], na * xa.x);
            atomicAdd(&y[lc * 5 + 1], na * xa.y);
            atomicAdd(&y[lc * 5 + 2], na * xa.z);
        }
        __syncthreads();
        for (int nn = threadIdx.x; nn < NPB; nn += blockDim.x) {
            int node = bk * NPB + nn;
            if (node < nc) {
                float d = dcl[nn];
                float4 xs = xs4[node];
                y4[node] = make_float4(fmaf(d, xs.x, y[nn * 5 + 0]),
                                       fmaf(d, xs.y, y[nn * 5 + 1]),
                                       fmaf(d, xs.z, y[nn * 5 + 2]), 1.0f);
            }
        }
    }
}

__global__ void k_pairs(const int* __restrict__ src, const int* __restrict__ dst, int P_,
                        const float* __restrict__ s_t, const float4* __restrict__ y4,
                        const float* __restrict__ G, const float* __restrict__ b_lin,
                        float* __restrict__ out) {
    int p = blockIdx.x * blockDim.x + threadIdx.x;
    if (p >= P_) return;
    float zs[6], zd[6];
    load_zf(src[p], s_t, y4, zs);
    load_zf(dst[p], s_t, y4, zd);
    float acc = 0.0f;
#pragma unroll
    for (int a = 0; a < 6; a++) {
        float g = 0.0f;
#pragma unroll
        for (int b = 0; b < 6; b++) g = fmaf(G[a * 6 + b], zd[b], g);
        acc = fmaf(zs[a], g, acc);
    }
    out[p] = acc + b_lin[0];
}

// ============ round-1 fallback (global-atomic path) ============

__global__ void k_G(const float* __restrict__ Wt, const float* __restrict__ bt,
                    const float* __restrict__ Wc, const float* __restrict__ bc,
                    const float* __restrict__ wlin, float* __restrict__ G) {
    int l = threadIdx.x;
    float acc[21];
#pragma unroll
    for (int k = 0; k < 21; k++) acc[k] = 0.0f;
    for (int h = l; h < 128; h += 64) {
        float m[6] = {Wt[h], bt[h], Wc[h], Wc[128 + h], Wc[256 + h], bc[h]};
        float w = wlin[h];
        int k = 0;
#pragma unroll
        for (int a = 0; a < 6; a++)
#pragma unroll
            for (int b = a; b < 6; b++)
                acc[k++] += m[a] * m[b] * w;
    }
    int k = 0;
#pragma unroll
    for (int a = 0; a < 6; a++)
#pragma unroll
        for (int b = a; b < 6; b++) {
            float v = acc[k++];
#pragma unroll
            for (int off = 32; off; off >>= 1) v += __shfl_down(v, off);
            if (l == 0) {
                G[a * 6 + b] = v;
                G[b * 6 + a] = v;
            }
        }
}

__global__ void k_deg(const int* __restrict__ tcol, const int* __restrict__ ccol,
                      const float* __restrict__ ew, int E_,
                      int* __restrict__ cnt_t, float* __restrict__ degw_c) {
    int i = blockIdx.x * blockDim.x + threadIdx.x;
    if (i >= E_) return;
    atomicAdd(&cnt_t[tcol[i]], 1);
    atomicAdd(&degw_c[ccol[i]], ew[i]);
}

__global__ void k_dis(const int* __restrict__ cnt_t, const float* __restrict__ degw_c,
                      float* __restrict__ dis_t, float* __restrict__ dis_c,
                      int nt, int nc) {
    int i = blockIdx.x * blockDim.x + threadIdx.x;
    if (i < nt) dis_t[i] = rsqrtf((float)cnt_t[i] + 1.0f);
    if (i < nc) dis_c[i] = rsqrtf(degw_c[i] + 1.0f);
}

__global__ void k_scat(const int* __restrict__ trow, const int* __restrict__ tcol,
                       const int* __restrict__ crow, const int* __restrict__ ccol,
                       const float* __restrict__ ew, int E_,
                       const float* __restrict__ dis_t, const float* __restrict__ dis_c,
                       const float* __restrict__ x_car,
                       float* __restrict__ sumdis, float* __restrict__ y4) {
    int i = blockIdx.x * blockDim.x + threadIdx.x;
    if (i >= E_) return;
    atomicAdd(&sumdis[tcol[i]], dis_t[trow[i]]);
    int r = crow[i], c = ccol[i];
    float nrm = dis_c[r] * ew[i] * dis_c[c];
    atomicAdd(&y4[c * 4 + 0], nrm * x_car[r * 3 + 0]);
    atomicAdd(&y4[c * 4 + 1], nrm * x_car[r * 3 + 1]);
    atomicAdd(&y4[c * 4 + 2], nrm * x_car[r * 3 + 2]);
}

__global__ void k_fin(int nt, int nc,
                      const float* __restrict__ dis_t, const float* __restrict__ sumdis,
                      float* __restrict__ s_t,
                      const float* __restrict__ dis_c, const float* __restrict__ x_car,
                      float* __restrict__ y4) {
    int i = blockIdx.x * blockDim.x + threadIdx.x;
    if (i < nt) {
        float d = dis_t[i];
        s_t[i] = d * sumdis[i] + d * d;
    }
    if (i < nc) {
        float d2 = dis_c[i] * dis_c[i];
        y4[i * 4 + 0] += d2 * x_car[i * 3 + 0];
        y4[i * 4 + 1] += d2 * x_car[i * 3 + 1];
        y4[i * 4 + 2] += d2 * x_car[i * 3 + 2];
        y4[i * 4 + 3] = 1.0f;
    }
}

// ============ launch ============

extern "C" void kernel_launch(void* const* d_in, const int* in_sizes, int n_in,
                              void* d_out, int out_size, void* d_ws, size_t ws_size,
                              hipStream_t stream) {
    const float* x_car  = (const float*)d_in[0];
    const int*   ei_t   = (const int*)d_in[1];
    const int*   ei_c   = (const int*)d_in[2];
    const float* ew_c   = (const float*)d_in[3];
    const int*   src    = (const int*)d_in[4];
    const int*   dst    = (const int*)d_in[5];
    const float* W_t    = (const float*)d_in[7];
    const float* b_t    = (const float*)d_in[8];
    const float* W_c    = (const float*)d_in[9];
    const float* b_c    = (const float*)d_in[10];
    const float* W_lin  = (const float*)d_in[11];
    const float* b_lin  = (const float*)d_in[12];
    float* out = (float*)d_out;

    const int NC = in_sizes[0] / 3;   // 100000
    const int E_ = in_sizes[1] / 2;   // 1600000
    const int P_ = in_sizes[4];       // 200000

    const int* trow = ei_t;  const int* tcol = ei_t + E_;
    const int* crow = ei_c;  const int* ccol = ei_c + E_;

    char* ws = (char*)d_ws;
    int gP = (P_ + BLK - 1) / BLK;
    int chunk = (E_ + PB - 1) / PB;

    // ---- try fused cooperative path ----
    bool fused_ok = false;
    if (ws_size >= WS_NEED_F && chunk <= CHUNK_MAX && NB * NPB >= N_TRUCK &&
        NB * NPB >= NC && NC <= 131072 && NB * CAP >= E_ + CAP) {
        int dev = 0, coop = 0, nblk = 0, cus = 0;
        if (hipGetDevice(&dev) == hipSuccess &&
            hipDeviceGetAttribute(&coop, hipDeviceAttributeCooperativeLaunch, dev) == hipSuccess &&
            coop &&
            hipOccupancyMaxActiveBlocksPerMultiprocessor(&nblk, (const void*)k_fused, BLK_P, 0) == hipSuccess &&
            hipDeviceGetAttribute(&cus, hipDeviceAttributeMultiprocessorCount, dev) == hipSuccess &&
            nblk * cus >= PB) {
            FParams fpar;
            fpar.trow = trow; fpar.tcol = tcol; fpar.crow = crow; fpar.ccol = ccol;
            fpar.ew = ew_c; fpar.src = src; fpar.dst = dst;
            fpar.Wt = W_t; fpar.bt = b_t; fpar.Wc = W_c; fpar.bc = b_c;
            fpar.wlin = W_lin; fpar.blin = b_lin;
            fpar.x_car = x_car; fpar.out = out;
            fpar.E = E_; fpar.P = P_; fpar.NC = NC;
            fpar.G     = (float*)(ws + 0);
            fpar.totT  = (int*)(ws + 256);
            fpar.totC  = (int*)(ws + 1280);
            fpar.cntT  = (int*)(ws + 4096);
            fpar.cntC  = (int*)(ws + 528384);
            fpar.dis_t = (float*)(ws + 1052672);
            fpar.dis_c = (float*)(ws + 1452672);
            fpar.s_t   = (float*)(ws + 1852672);
            fpar.y4    = (float4*)(ws + 2252672);
            fpar.xs4   = (float4*)(ws + 3852672);
            fpar.pT    = (unsigned*)(ws + 5452672);
            fpar.pC8   = (u64*)(ws + 13841280);
            void* args[] = {(void*)&fpar};
            if (hipLaunchCooperativeKernel((const void*)k_fused, dim3(PB), dim3(BLK_P),
                                           args, 0, stream) == hipSuccess)
                fused_ok = true;
        }
    }
    if (fused_ok) return;

    // ---- round-6 multi-dispatch fallback ----
    if (ws_size >= WS_NEED_NEW && chunk <= CHUNK_MAX && NB * NPB >= N_TRUCK &&
        NB * NPB >= NC && NB * CAP >= E_ + 8192) {
        int*      curT  = (int*)(ws + 0);
        int*      curC  = (int*)(ws + 1024);
        float*    G     = (float*)(ws + 2048);
        float*    dis_t = (float*)(ws + 4096);
        float*    dis_c = (float*)(ws + 404096);
        float*    s_t   = (float*)(ws + 804096);
        float*    y4    = (float*)(ws + 1204096);
        float4*   xs4   = (float4*)(ws + 2804096);
        unsigned* pT    = (unsigned*)(ws + 4404096);
        u64*      pC8   = (u64*)(ws + 12792704);

        hipMemsetAsync(ws, 0, 2048, stream);
        k_place<<<PB + 1, BLK_P, 0, stream>>>(trow, tcol, crow, ccol, ew_c, E_,
                                              curT, curC, pT, pC8,
                                              W_t, b_t, W_c, b_c, W_lin, G);
        k_deg2<<<2 * NB, BLK_P, 0, stream>>>(pT, pC8, curT, curC, x_car,
                                             dis_t, dis_c, xs4, N_TRUCK, NC);
        k_agg<<<2 * NB, BLK_P, 0, stream>>>(pT, pC8, curT, curC, dis_t, dis_c,
                                            xs4, s_t, (float4*)y4, N_TRUCK, NC);
        k_pairs<<<gP, BLK, 0, stream>>>(src, dst, P_, s_t, (const float4*)y4, G, b_lin, out);
    } else {
        // round-1 global-atomic fallback (~4 MB ws)
        int*   cnt_t  = (int*)(ws + 0);
        float* sumdis = (float*)(ws + 400000);
        float* degw_c = (float*)(ws + 800000);
        float* y4     = (float*)(ws + 1200000);
        float* dis_t  = (float*)(ws + 2800000);
        float* dis_c  = (float*)(ws + 3200000);
        float* s_t    = (float*)(ws + 3600000);
        float* G      = (float*)(ws + 4000000);

        hipMemsetAsync(ws, 0, 2800000, stream);
        int gE = (E_ + BLK - 1) / BLK;
        int gN = ((N_TRUCK > NC ? N_TRUCK : NC) + BLK - 1) / BLK;
        k_deg<<<gE, BLK, 0, stream>>>(tcol, ccol, ew_c, E_, cnt_t, degw_c);
        k_dis<<<gN, BLK, 0, stream>>>(cnt_t, degw_c, dis_t, dis_c, N_TRUCK, NC);
        k_scat<<<gE, BLK, 0, stream>>>(trow, tcol, crow, ccol, ew_c, E_,
                                       dis_t, dis_c, x_car, sumdis, y4);
        k_fin<<<gN, BLK, 0, stream>>>(N_TRUCK, NC, dis_t, sumdis, s_t, dis_c, x_car, y4);
        k_G<<<1, 64, 0, stream>>>(W_t, b_t, W_c, b_c, W_lin, G);
        k_pairs<<<gP, BLK, 0, stream>>>(src, dst, P_, s_t, (const float4*)y4, G, b_lin, out);
    }
}